// Round 2
// baseline (1425.637 us; speedup 1.0000x reference)
//
#include <hip/hip_runtime.h>

// DART_Net fused kernel, MI355X (gfx950). Round 2.
// B=64, N=128, M=64, LH=LO=128. Output [B*N] fp32.
//
// R2 changes vs R1 (which was latency-bound: occ 20%, VALU 57%, MFMA 6%):
//  - G=8 atoms/block, grid 1024, __launch_bounds__(256,4) -> 4 blocks/CU
//    (16 waves/CU) instead of 2 (8 waves/CU). VGPR must stay <=128.
//  - ballot-based row masks (2 v_cmp per atom) replace 8 ds_bpermute.
//  - sW1 padded (+1 f32x4 per 8 channels): layer-1 ds_read_b128 was 4-way
//    same-bank (lq stride = 128B = bank wrap); now lq groups 144B apart.
//  - prefetch next atom's x rows at top of atom loop.
//  - b2 read from LDS in epilogue (frees 4 VGPR for the prefetch).

typedef __attribute__((ext_vector_type(8))) short short8;   // bf16x8 frag (4 VGPR)
typedef __attribute__((ext_vector_type(4))) float f32x4;    // acc frag / float4

#define G_ 8
#define NATOMS (64 * 128)

struct DartParams {
  const float* x[4];    // aj, ak, al, ai
  const float* W1[4];   // [128][3]  (j,k,l,i)
  const float* b1[4];   // [128]
  const float* W2[4];   // [128][128]
  const float* b2[4];   // [128]
  const float* HW[4];   // 64x128, 32x64, 16x32, 1x16
  const float* Hb[4];
  float* out;
};

__device__ __forceinline__ float celu01(float z) {
  // celu(z, alpha=0.1) = max(z,0) + min(0.1*(exp(10z)-1), 0)
  float e = __builtin_amdgcn_exp2f(z * 14.42695040888963f);  // exp(10z)
  return fmaxf(z, 0.0f) + fminf(fmaf(0.1f, e, -0.1f), 0.0f);
}

__device__ __forceinline__ short f2bf(float f) {
  unsigned u = __builtin_bit_cast(unsigned, f);
  u += 0x7fffu + ((u >> 16) & 1u);   // RNE
  return (short)(u >> 16);
}

extern "C" __global__ __launch_bounds__(256, 4)
void dart_fused(DartParams p) {
  __shared__ f32x4 sW1[4][144];      // {w0,w1,w2,b}, padded: idx = c + (c>>3)
  __shared__ float sB2[4][128];
  __shared__ float sAtm[G_][128];
  __shared__ float sImask[G_];
  __shared__ float sH1[G_][64];
  __shared__ float sH2[G_][32];
  __shared__ float sH3[G_][16];

  const int t    = threadIdx.x;
  const int lane = t & 63;
  const int wave = t >> 6;       // 0..3
  const int wr   = wave >> 1;    // row half (0,1)
  const int wc   = wave & 1;     // col half (0,1)
  const int lq   = lane >> 4;    // lane quarter
  const int lr   = lane & 15;
  const int atom0 = (int)blockIdx.x * G_;

  // ---- stage layer-1 weights (packed float4, padded) and layer-2 biases ----
#pragma unroll
  for (int s = 0; s < 4; ++s) {
    if (t < 128) {
      const float* w = p.W1[s] + t * 3;
      f32x4 v;
      v.x = w[0]; v.y = w[1]; v.z = w[2]; v.w = p.b1[s][t];
      sW1[s][t + (t >> 3)] = v;
      sB2[s][t] = p.b2[s][t];
    }
  }
  for (int i = t; i < G_ * 128; i += 256) (&sAtm[0][0])[i] = 0.0f;
  __syncthreads();

  short8 bfr[4][4];   // B fragments [ob][kb], held across the atom loop

  // ---------------- species j, k, l ----------------
#pragma unroll
  for (int s = 0; s < 3; ++s) {
    const float* W2 = p.W2[s];
#pragma unroll
    for (int ob = 0; ob < 4; ++ob) {
#pragma unroll
      for (int kb = 0; kb < 4; ++kb) {
        const f32x4* src = (const f32x4*)(W2 + (wc * 64 + ob * 16 + lr) * 128 + kb * 32 + lq * 8);
        f32x4 lo = src[0], hi = src[1];
        short8 f;
        f[0] = f2bf(lo.x); f[1] = f2bf(lo.y); f[2] = f2bf(lo.z); f[3] = f2bf(lo.w);
        f[4] = f2bf(hi.x); f[5] = f2bf(hi.y); f[6] = f2bf(hi.z); f[7] = f2bf(hi.w);
        bfr[ob][kb] = f;
      }
    }

    const float* X = p.x[s];
    const f32x4* sW1p = &sW1[s][0];

    // prefetch atom 0's x rows
    float px[2][3];
#pragma unroll
    for (int rb = 0; rb < 2; ++rb) {
      const float* xp = X + (atom0 * 64 + wr * 32 + rb * 16 + lr) * 3;
      px[rb][0] = xp[0]; px[rb][1] = xp[1]; px[rb][2] = xp[2];
    }

#pragma unroll 1
    for (int g = 0; g < G_; ++g) {
      float x0[2], x1[2], x2[2];
      bool mA[2];
#pragma unroll
      for (int rb = 0; rb < 2; ++rb) {
        x0[rb] = px[rb][0]; x1[rb] = px[rb][1]; x2[rb] = px[rb][2];
        mA[rb] = ((x0[rb] + x1[rb] + x2[rb]) != 0.0f);
      }
      if (g + 1 < G_) {
#pragma unroll
        for (int rb = 0; rb < 2; ++rb) {
          const float* xp = X + ((atom0 + g + 1) * 64 + wr * 32 + rb * 16 + lr) * 3;
          px[rb][0] = xp[0]; px[rb][1] = xp[1]; px[rb][2] = xp[2];
        }
      }
      const unsigned long long mb0 = __ballot(mA[0]);
      const unsigned long long mb1 = __ballot(mA[1]);

      // ---- layer 1 + celu + pack, directly in A-fragment layout ----
      short8 af[2][4];
#pragma unroll
      for (int kb = 0; kb < 4; ++kb) {
        const f32x4* wrow = sW1p + kb * 36 + lq * 9;   // padded index
        short8 f0, f1;
#pragma unroll
        for (int e = 0; e < 8; ++e) {
          f32x4 w = wrow[e];
          f0[e] = f2bf(celu01(fmaf(x0[0], w.x, fmaf(x1[0], w.y, fmaf(x2[0], w.z, w.w)))));
          f1[e] = f2bf(celu01(fmaf(x0[1], w.x, fmaf(x1[1], w.y, fmaf(x2[1], w.z, w.w)))));
        }
        af[0][kb] = f0; af[1][kb] = f1;
      }

      // ---- layer 2 GEMM (64x128 per atom, this wave: 32 rows x 64 cols) ----
      f32x4 acc[2][4];
#pragma unroll
      for (int rb = 0; rb < 2; ++rb)
#pragma unroll
        for (int ob = 0; ob < 4; ++ob) {
          f32x4 a = {0.0f, 0.0f, 0.0f, 0.0f};
#pragma unroll
          for (int kb = 0; kb < 4; ++kb)
            a = __builtin_amdgcn_mfma_f32_16x16x32_bf16(af[rb][kb], bfr[ob][kb], a, 0, 0, 0);
          acc[rb][ob] = a;
        }

      // ---- bias + celu + mask + row-sum -> atm ----
#pragma unroll
      for (int ob = 0; ob < 4; ++ob) {
        const int col = wc * 64 + ob * 16 + lr;
        const float b2v = sB2[s][col];
        float part = 0.0f;
#pragma unroll
        for (int j = 0; j < 4; ++j) {
          const int bit = lq * 4 + j;
          float v0 = celu01(acc[0][ob][j] + b2v);
          float v1 = celu01(acc[1][ob][j] + b2v);
          part += ((mb0 >> bit) & 1ull) ? v0 : 0.0f;
          part += ((mb1 >> bit) & 1ull) ? v1 : 0.0f;
        }
        part += __shfl_xor(part, 16, 64);
        part += __shfl_xor(part, 32, 64);
        if (lane < 16) atomicAdd(&sAtm[g][col], part);
      }
    }
  }

  // ---------------- species i: one 16-row GEMM (rows = atoms) ----------------
  {
    const float* W2 = p.W2[3];
#pragma unroll
    for (int ob = 0; ob < 4; ++ob) {
#pragma unroll
      for (int kb = 0; kb < 4; ++kb) {
        const f32x4* src = (const f32x4*)(W2 + (wc * 64 + ob * 16 + lr) * 128 + kb * 32 + lq * 8);
        f32x4 lo = src[0], hi = src[1];
        short8 f;
        f[0] = f2bf(lo.x); f[1] = f2bf(lo.y); f[2] = f2bf(lo.z); f[3] = f2bf(lo.w);
        f[4] = f2bf(hi.x); f[5] = f2bf(hi.y); f[6] = f2bf(hi.z); f[7] = f2bf(hi.w);
        bfr[ob][kb] = f;
      }
    }
    // 16-row GEMM covers atoms atom0..atom0+15; only g < G_ results are used.
    const int ri = min(atom0 + lr, NATOMS - 1);
    const float* xp = p.x[3] + ri * 3;
    const float x0 = xp[0], x1 = xp[1], x2 = xp[2];
    const bool mI = ((x0 + x1 + x2) != 0.0f);
    const unsigned long long mbi = __ballot(mI);

    short8 af[4];
    const f32x4* sW1p = &sW1[3][0];
#pragma unroll
    for (int kb = 0; kb < 4; ++kb) {
      const f32x4* wrow = sW1p + kb * 36 + lq * 9;
      short8 f;
#pragma unroll
      for (int e = 0; e < 8; ++e) {
        f32x4 w = wrow[e];
        f[e] = f2bf(celu01(fmaf(x0, w.x, fmaf(x1, w.y, fmaf(x2, w.z, w.w)))));
      }
      af[kb] = f;
    }
    f32x4 acc[4];
#pragma unroll
    for (int ob = 0; ob < 4; ++ob) {
      f32x4 a = {0.0f, 0.0f, 0.0f, 0.0f};
#pragma unroll
      for (int kb = 0; kb < 4; ++kb)
        a = __builtin_amdgcn_mfma_f32_16x16x32_bf16(af[kb], bfr[ob][kb], a, 0, 0, 0);
      acc[ob] = a;
    }
    __syncthreads();   // all j/k/l atomics complete before exclusive adds
    if (wave == 0 && t < G_) sImask[t] = mI ? 1.0f : 0.0f;
    if (wr == 0) {
#pragma unroll
      for (int ob = 0; ob < 4; ++ob) {
        const int col = wc * 64 + ob * 16 + lr;
        const float b2v = sB2[3][col];
#pragma unroll
        for (int j = 0; j < 4; ++j) {
          const int g = lq * 4 + j;
          if (g < G_) {
            float m = ((mbi >> g) & 1ull) ? 1.0f : 0.0f;
            sAtm[g][col] += celu01(acc[ob][j] + b2v) * m;
          }
        }
      }
    }
    __syncthreads();
  }

  // ---------------- head MLP: 128 -> 64 -> 32 -> 16 -> 1 ----------------
  {
    const int g = t >> 4, u = t & 15;
    const bool act = (g < G_);
    if (act) {
      const f32x4* atm4 = (const f32x4*)sAtm[g];
#pragma unroll
      for (int rep = 0; rep < 4; ++rep) {
        const int o = rep * 16 + u;
        const f32x4* w4 = (const f32x4*)(p.HW[0] + o * 128);
        float z = p.Hb[0][o];
#pragma unroll 8
        for (int c = 0; c < 32; ++c) {
          f32x4 a = atm4[c], w = w4[c];
          z = fmaf(a.x, w.x, fmaf(a.y, w.y, fmaf(a.z, w.z, fmaf(a.w, w.w, z))));
        }
        sH1[g][o] = celu01(z);
      }
    }
    __syncthreads();
    if (act) {
      const f32x4* h14 = (const f32x4*)sH1[g];
#pragma unroll
      for (int rep = 0; rep < 2; ++rep) {
        const int o = rep * 16 + u;
        const f32x4* w4 = (const f32x4*)(p.HW[1] + o * 64);
        float z = p.Hb[1][o];
#pragma unroll
        for (int c = 0; c < 16; ++c) {
          f32x4 a = h14[c], w = w4[c];
          z = fmaf(a.x, w.x, fmaf(a.y, w.y, fmaf(a.z, w.z, fmaf(a.w, w.w, z))));
        }
        sH2[g][o] = celu01(z);
      }
    }
    __syncthreads();
    if (act) {
      const f32x4* h24 = (const f32x4*)sH2[g];
      const f32x4* w4 = (const f32x4*)(p.HW[2] + u * 32);
      float z = p.Hb[2][u];
#pragma unroll
      for (int c = 0; c < 8; ++c) {
        f32x4 a = h24[c], w = w4[c];
        z = fmaf(a.x, w.x, fmaf(a.y, w.y, fmaf(a.z, w.z, fmaf(a.w, w.w, z))));
      }
      sH3[g][u] = celu01(z);
    }
    __syncthreads();
    if (act && u == 0) {
      const f32x4* h34 = (const f32x4*)sH3[g];
      const f32x4* w4 = (const f32x4*)p.HW[3];
      float z = p.Hb[3][0];
#pragma unroll
      for (int c = 0; c < 4; ++c) {
        f32x4 a = h34[c], w = w4[c];
        z = fmaf(a.x, w.x, fmaf(a.y, w.y, fmaf(a.z, w.z, fmaf(a.w, w.w, z))));
      }
      p.out[atom0 + g] = z * sImask[g];
    }
  }
}

extern "C" void kernel_launch(void* const* d_in, const int* in_sizes, int n_in,
                              void* d_out, int out_size, void* d_ws, size_t ws_size,
                              hipStream_t stream) {
  (void)in_sizes; (void)n_in; (void)out_size; (void)d_ws; (void)ws_size;
  DartParams p;
  // dict order: ai aj ak al | Wi1 bi1 Wi2 bi2 | Wj1 bj1 Wj2 bj2 | Wk1 bk1 Wk2 bk2
  //             | Wl1 bl1 Wl2 bl2 | W1 b1 W2 b2 W3 b3 W4 b4
  p.x[0] = (const float*)d_in[1];   // aj
  p.x[1] = (const float*)d_in[2];   // ak
  p.x[2] = (const float*)d_in[3];   // al
  p.x[3] = (const float*)d_in[0];   // ai
  p.W1[0] = (const float*)d_in[8];  p.b1[0] = (const float*)d_in[9];
  p.W2[0] = (const float*)d_in[10]; p.b2[0] = (const float*)d_in[11];
  p.W1[1] = (const float*)d_in[12]; p.b1[1] = (const float*)d_in[13];
  p.W2[1] = (const float*)d_in[14]; p.b2[1] = (const float*)d_in[15];
  p.W1[2] = (const float*)d_in[16]; p.b1[2] = (const float*)d_in[17];
  p.W2[2] = (const float*)d_in[18]; p.b2[2] = (const float*)d_in[19];
  p.W1[3] = (const float*)d_in[4];  p.b1[3] = (const float*)d_in[5];
  p.W2[3] = (const float*)d_in[6];  p.b2[3] = (const float*)d_in[7];
  p.HW[0] = (const float*)d_in[20]; p.Hb[0] = (const float*)d_in[21];
  p.HW[1] = (const float*)d_in[22]; p.Hb[1] = (const float*)d_in[23];
  p.HW[2] = (const float*)d_in[24]; p.Hb[2] = (const float*)d_in[25];
  p.HW[3] = (const float*)d_in[26]; p.Hb[3] = (const float*)d_in[27];
  p.out = (float*)d_out;

  dart_fused<<<dim3((NATOMS + G_ - 1) / G_), dim3(256), 0, stream>>>(p);
}

// Round 3
// 559.199 us; speedup vs baseline: 2.5494x; 2.5494x over previous
//
#include <hip/hip_runtime.h>

// DART_Net fused kernel, MI355X (gfx950). Round 3.
// B=64, N=128, M=64, LH=LO=128. Output [B*N] fp32.
//
// R3 vs R2: R2's __launch_bounds__(256,4) capped arch VGPRs at 64 -> bfr[4][4]
// (64 VGPRs) spilled to scratch -> 4.2 GB FETCH, 1.4 ms. Revert to (256,2)
// (proven 128-VGPR no-spill in R1) and get occupancy from the GRID instead:
// G=8 atoms/block, 1024 blocks = 4 blocks/CU available (R1 was grid-limited
// at 2). Keep R2's ballot masks, padded sW1, x-prefetch. Split af live range
// (af0 -> MFMA rb0 -> af1 -> MFMA rb1) to cut ~16 concurrent VGPRs and let
// rb1 layer-1 VALU overlap rb0 MFMAs.

typedef __attribute__((ext_vector_type(8))) short short8;   // bf16x8 frag (4 VGPR)
typedef __attribute__((ext_vector_type(4))) float f32x4;    // acc frag / float4

#define G_ 8
#define NATOMS (64 * 128)

struct DartParams {
  const float* x[4];    // aj, ak, al, ai
  const float* W1[4];   // [128][3]  (j,k,l,i)
  const float* b1[4];   // [128]
  const float* W2[4];   // [128][128]
  const float* b2[4];   // [128]
  const float* HW[4];   // 64x128, 32x64, 16x32, 1x16
  const float* Hb[4];
  float* out;
};

__device__ __forceinline__ float celu01(float z) {
  // celu(z, alpha=0.1) = max(z,0) + min(0.1*(exp(10z)-1), 0)
  float e = __builtin_amdgcn_exp2f(z * 14.42695040888963f);  // exp(10z)
  return fmaxf(z, 0.0f) + fminf(fmaf(0.1f, e, -0.1f), 0.0f);
}

__device__ __forceinline__ short f2bf(float f) {
  unsigned u = __builtin_bit_cast(unsigned, f);
  u += 0x7fffu + ((u >> 16) & 1u);   // RNE
  return (short)(u >> 16);
}

extern "C" __global__ __launch_bounds__(256, 2)
void dart_fused(DartParams p) {
  __shared__ f32x4 sW1[4][144];      // {w0,w1,w2,b}, padded: idx = c + (c>>3)
  __shared__ float sB2[4][128];
  __shared__ float sAtm[G_][128];
  __shared__ float sImask[G_];
  __shared__ float sH1[G_][64];
  __shared__ float sH2[G_][32];
  __shared__ float sH3[G_][16];

  const int t    = threadIdx.x;
  const int lane = t & 63;
  const int wave = t >> 6;       // 0..3
  const int wr   = wave >> 1;    // row half (0,1)
  const int wc   = wave & 1;     // col half (0,1)
  const int lq   = lane >> 4;    // lane quarter
  const int lr   = lane & 15;
  const int atom0 = (int)blockIdx.x * G_;

  // ---- stage layer-1 weights (packed float4, padded) and layer-2 biases ----
#pragma unroll
  for (int s = 0; s < 4; ++s) {
    if (t < 128) {
      const float* w = p.W1[s] + t * 3;
      f32x4 v;
      v.x = w[0]; v.y = w[1]; v.z = w[2]; v.w = p.b1[s][t];
      sW1[s][t + (t >> 3)] = v;
      sB2[s][t] = p.b2[s][t];
    }
  }
  for (int i = t; i < G_ * 128; i += 256) (&sAtm[0][0])[i] = 0.0f;
  __syncthreads();

  short8 bfr[4][4];   // B fragments [ob][kb], held across the atom loop

  // ---------------- species j, k, l ----------------
#pragma unroll
  for (int s = 0; s < 3; ++s) {
    const float* W2 = p.W2[s];
#pragma unroll
    for (int ob = 0; ob < 4; ++ob) {
#pragma unroll
      for (int kb = 0; kb < 4; ++kb) {
        const f32x4* src = (const f32x4*)(W2 + (wc * 64 + ob * 16 + lr) * 128 + kb * 32 + lq * 8);
        f32x4 lo = src[0], hi = src[1];
        short8 f;
        f[0] = f2bf(lo.x); f[1] = f2bf(lo.y); f[2] = f2bf(lo.z); f[3] = f2bf(lo.w);
        f[4] = f2bf(hi.x); f[5] = f2bf(hi.y); f[6] = f2bf(hi.z); f[7] = f2bf(hi.w);
        bfr[ob][kb] = f;
      }
    }

    const float* X = p.x[s];
    const f32x4* sW1p = &sW1[s][0];

    // prefetch atom 0's x rows
    float px[2][3];
#pragma unroll
    for (int rb = 0; rb < 2; ++rb) {
      const float* xp = X + (atom0 * 64 + wr * 32 + rb * 16 + lr) * 3;
      px[rb][0] = xp[0]; px[rb][1] = xp[1]; px[rb][2] = xp[2];
    }

#pragma unroll 1
    for (int g = 0; g < G_; ++g) {
      float x0[2], x1[2], x2[2];
      bool mA[2];
#pragma unroll
      for (int rb = 0; rb < 2; ++rb) {
        x0[rb] = px[rb][0]; x1[rb] = px[rb][1]; x2[rb] = px[rb][2];
        mA[rb] = ((x0[rb] + x1[rb] + x2[rb]) != 0.0f);
      }
      if (g + 1 < G_) {
#pragma unroll
        for (int rb = 0; rb < 2; ++rb) {
          const float* xp = X + ((atom0 + g + 1) * 64 + wr * 32 + rb * 16 + lr) * 3;
          px[rb][0] = xp[0]; px[rb][1] = xp[1]; px[rb][2] = xp[2];
        }
      }
      const unsigned long long mb0 = __ballot(mA[0]);
      const unsigned long long mb1 = __ballot(mA[1]);

      // ---- layer 1 + celu + pack (A-frag layout), interleaved with MFMA ----
      f32x4 acc[2][4];
      short8 af0[4];
#pragma unroll
      for (int kb = 0; kb < 4; ++kb) {
        const f32x4* wrow = sW1p + kb * 36 + lq * 9;   // padded index
        short8 f0;
#pragma unroll
        for (int e = 0; e < 8; ++e) {
          f32x4 w = wrow[e];
          f0[e] = f2bf(celu01(fmaf(x0[0], w.x, fmaf(x1[0], w.y, fmaf(x2[0], w.z, w.w)))));
        }
        af0[kb] = f0;
      }
#pragma unroll
      for (int ob = 0; ob < 4; ++ob) {
        f32x4 a = {0.0f, 0.0f, 0.0f, 0.0f};
#pragma unroll
        for (int kb = 0; kb < 4; ++kb)
          a = __builtin_amdgcn_mfma_f32_16x16x32_bf16(af0[kb], bfr[ob][kb], a, 0, 0, 0);
        acc[0][ob] = a;
      }
      short8 af1[4];
#pragma unroll
      for (int kb = 0; kb < 4; ++kb) {
        const f32x4* wrow = sW1p + kb * 36 + lq * 9;
        short8 f1;
#pragma unroll
        for (int e = 0; e < 8; ++e) {
          f32x4 w = wrow[e];
          f1[e] = f2bf(celu01(fmaf(x0[1], w.x, fmaf(x1[1], w.y, fmaf(x2[1], w.z, w.w)))));
        }
        af1[kb] = f1;
      }
#pragma unroll
      for (int ob = 0; ob < 4; ++ob) {
        f32x4 a = {0.0f, 0.0f, 0.0f, 0.0f};
#pragma unroll
        for (int kb = 0; kb < 4; ++kb)
          a = __builtin_amdgcn_mfma_f32_16x16x32_bf16(af1[kb], bfr[ob][kb], a, 0, 0, 0);
        acc[1][ob] = a;
      }

      // ---- bias + celu + mask + row-sum -> atm ----
#pragma unroll
      for (int ob = 0; ob < 4; ++ob) {
        const int col = wc * 64 + ob * 16 + lr;
        const float b2v = sB2[s][col];
        float part = 0.0f;
#pragma unroll
        for (int j = 0; j < 4; ++j) {
          const int bit = lq * 4 + j;
          float v0 = celu01(acc[0][ob][j] + b2v);
          float v1 = celu01(acc[1][ob][j] + b2v);
          part += ((mb0 >> bit) & 1ull) ? v0 : 0.0f;
          part += ((mb1 >> bit) & 1ull) ? v1 : 0.0f;
        }
        part += __shfl_xor(part, 16, 64);
        part += __shfl_xor(part, 32, 64);
        if (lane < 16) atomicAdd(&sAtm[g][col], part);
      }
    }
  }

  // ---------------- species i: one 16-row GEMM (rows = atoms) ----------------
  {
    const float* W2 = p.W2[3];
#pragma unroll
    for (int ob = 0; ob < 4; ++ob) {
#pragma unroll
      for (int kb = 0; kb < 4; ++kb) {
        const f32x4* src = (const f32x4*)(W2 + (wc * 64 + ob * 16 + lr) * 128 + kb * 32 + lq * 8);
        f32x4 lo = src[0], hi = src[1];
        short8 f;
        f[0] = f2bf(lo.x); f[1] = f2bf(lo.y); f[2] = f2bf(lo.z); f[3] = f2bf(lo.w);
        f[4] = f2bf(hi.x); f[5] = f2bf(hi.y); f[6] = f2bf(hi.z); f[7] = f2bf(hi.w);
        bfr[ob][kb] = f;
      }
    }
    // 16-row GEMM covers atoms atom0..atom0+15; only g < G_ results are used.
    const int ri = min(atom0 + lr, NATOMS - 1);
    const float* xp = p.x[3] + ri * 3;
    const float x0 = xp[0], x1 = xp[1], x2 = xp[2];
    const bool mI = ((x0 + x1 + x2) != 0.0f);
    const unsigned long long mbi = __ballot(mI);

    short8 af[4];
    const f32x4* sW1p = &sW1[3][0];
#pragma unroll
    for (int kb = 0; kb < 4; ++kb) {
      const f32x4* wrow = sW1p + kb * 36 + lq * 9;
      short8 f;
#pragma unroll
      for (int e = 0; e < 8; ++e) {
        f32x4 w = wrow[e];
        f[e] = f2bf(celu01(fmaf(x0, w.x, fmaf(x1, w.y, fmaf(x2, w.z, w.w)))));
      }
      af[kb] = f;
    }
    f32x4 acc[4];
#pragma unroll
    for (int ob = 0; ob < 4; ++ob) {
      f32x4 a = {0.0f, 0.0f, 0.0f, 0.0f};
#pragma unroll
      for (int kb = 0; kb < 4; ++kb)
        a = __builtin_amdgcn_mfma_f32_16x16x32_bf16(af[kb], bfr[ob][kb], a, 0, 0, 0);
      acc[ob] = a;
    }
    __syncthreads();   // all j/k/l atomics complete before exclusive adds
    if (wave == 0 && t < G_) sImask[t] = mI ? 1.0f : 0.0f;
    if (wr == 0) {
#pragma unroll
      for (int ob = 0; ob < 4; ++ob) {
        const int col = wc * 64 + ob * 16 + lr;
        const float b2v = sB2[3][col];
#pragma unroll
        for (int j = 0; j < 4; ++j) {
          const int g = lq * 4 + j;
          if (g < G_) {
            float m = ((mbi >> g) & 1ull) ? 1.0f : 0.0f;
            sAtm[g][col] += celu01(acc[ob][j] + b2v) * m;
          }
        }
      }
    }
    __syncthreads();
  }

  // ---------------- head MLP: 128 -> 64 -> 32 -> 16 -> 1 ----------------
  {
    const int g = t >> 4, u = t & 15;
    const bool act = (g < G_);
    if (act) {
      const f32x4* atm4 = (const f32x4*)sAtm[g];
#pragma unroll
      for (int rep = 0; rep < 4; ++rep) {
        const int o = rep * 16 + u;
        const f32x4* w4 = (const f32x4*)(p.HW[0] + o * 128);
        float z = p.Hb[0][o];
#pragma unroll 8
        for (int c = 0; c < 32; ++c) {
          f32x4 a = atm4[c], w = w4[c];
          z = fmaf(a.x, w.x, fmaf(a.y, w.y, fmaf(a.z, w.z, fmaf(a.w, w.w, z))));
        }
        sH1[g][o] = celu01(z);
      }
    }
    __syncthreads();
    if (act) {
      const f32x4* h14 = (const f32x4*)sH1[g];
#pragma unroll
      for (int rep = 0; rep < 2; ++rep) {
        const int o = rep * 16 + u;
        const f32x4* w4 = (const f32x4*)(p.HW[1] + o * 64);
        float z = p.Hb[1][o];
#pragma unroll
        for (int c = 0; c < 16; ++c) {
          f32x4 a = h14[c], w = w4[c];
          z = fmaf(a.x, w.x, fmaf(a.y, w.y, fmaf(a.z, w.z, fmaf(a.w, w.w, z))));
        }
        sH2[g][o] = celu01(z);
      }
    }
    __syncthreads();
    if (act) {
      const f32x4* h24 = (const f32x4*)sH2[g];
      const f32x4* w4 = (const f32x4*)(p.HW[2] + u * 32);
      float z = p.Hb[2][u];
#pragma unroll
      for (int c = 0; c < 8; ++c) {
        f32x4 a = h24[c], w = w4[c];
        z = fmaf(a.x, w.x, fmaf(a.y, w.y, fmaf(a.z, w.z, fmaf(a.w, w.w, z))));
      }
      sH3[g][u] = celu01(z);
    }
    __syncthreads();
    if (act && u == 0) {
      const f32x4* h34 = (const f32x4*)sH3[g];
      const f32x4* w4 = (const f32x4*)p.HW[3];
      float z = p.Hb[3][0];
#pragma unroll
      for (int c = 0; c < 4; ++c) {
        f32x4 a = h34[c], w = w4[c];
        z = fmaf(a.x, w.x, fmaf(a.y, w.y, fmaf(a.z, w.z, fmaf(a.w, w.w, z))));
      }
      p.out[atom0 + g] = z * sImask[g];
    }
  }
}

extern "C" void kernel_launch(void* const* d_in, const int* in_sizes, int n_in,
                              void* d_out, int out_size, void* d_ws, size_t ws_size,
                              hipStream_t stream) {
  (void)in_sizes; (void)n_in; (void)out_size; (void)d_ws; (void)ws_size;
  DartParams p;
  // dict order: ai aj ak al | Wi1 bi1 Wi2 bi2 | Wj1 bj1 Wj2 bj2 | Wk1 bk1 Wk2 bk2
  //             | Wl1 bl1 Wl2 bl2 | W1 b1 W2 b2 W3 b3 W4 b4
  p.x[0] = (const float*)d_in[1];   // aj
  p.x[1] = (const float*)d_in[2];   // ak
  p.x[2] = (const float*)d_in[3];   // al
  p.x[3] = (const float*)d_in[0];   // ai
  p.W1[0] = (const float*)d_in[8];  p.b1[0] = (const float*)d_in[9];
  p.W2[0] = (const float*)d_in[10]; p.b2[0] = (const float*)d_in[11];
  p.W1[1] = (const float*)d_in[12]; p.b1[1] = (const float*)d_in[13];
  p.W2[1] = (const float*)d_in[14]; p.b2[1] = (const float*)d_in[15];
  p.W1[2] = (const float*)d_in[16]; p.b1[2] = (const float*)d_in[17];
  p.W2[2] = (const float*)d_in[18]; p.b2[2] = (const float*)d_in[19];
  p.W1[3] = (const float*)d_in[4];  p.b1[3] = (const float*)d_in[5];
  p.W2[3] = (const float*)d_in[6];  p.b2[3] = (const float*)d_in[7];
  p.HW[0] = (const float*)d_in[20]; p.Hb[0] = (const float*)d_in[21];
  p.HW[1] = (const float*)d_in[22]; p.Hb[1] = (const float*)d_in[23];
  p.HW[2] = (const float*)d_in[24]; p.Hb[2] = (const float*)d_in[25];
  p.HW[3] = (const float*)d_in[26]; p.Hb[3] = (const float*)d_in[27];
  p.out = (float*)d_out;

  dart_fused<<<dim3((NATOMS + G_ - 1) / G_), dim3(256), 0, stream>>>(p);
}

// Round 4
// 248.742 us; speedup vs baseline: 5.7314x; 2.2481x over previous
//
#include <hip/hip_runtime.h>

// DART_Net fused kernel, MI355X (gfx950). Round 4.
// B=64, N=128, M=64, LH=LO=128. Output [B*N] fp32.
//
// R4 vs R3: R3 still spilled (WRITE_SIZE 425 MB vs 32 KB output) because
// bfr[4][4] (64 VGPR) + acc + af is structurally over the 128 budget.
// Evict B-fragments to LDS: pack bf16 W2 in per-lane MFMA fragment layout
// (sBf[2][16][64] = 32 KB), read back conflict-free (contiguous 16B/lane)
// just-in-time per (ob,kb). Per-ob epilogue keeps acc live range at 8 regs.
// W1/b2 staged per-species; head arrays union into dead sBf space ->
// 39.7 KB LDS/block -> 4 blocks/CU, grid 1024 = exactly 4/CU (16 waves/CU).

typedef __attribute__((ext_vector_type(8))) short short8;   // bf16x8 frag (4 VGPR)
typedef __attribute__((ext_vector_type(4))) float f32x4;    // acc frag / float4

#define G_ 8
#define NATOMS (64 * 128)

// LDS layout (bytes):
//   [    0, 32768)  sBf  : bf16 B-frags [wc][ob*4+kb][lane] (16B each)
//                   (after species done, reused: sH1 @0, sH2 @2048, sH3 @3072)
//   [32768, 35072)  sW1  : f32x4[144] {w0,w1,w2,b1}, padded idx = c + (c>>3)
//   [35072, 35584)  sB2  : float[128]
//   [35584, 39680)  sAtm : float[G_][128]
//   [39680, 39712)  sIm  : float[G_]
#define LDS_BYTES 39712

struct DartParams {
  const float* x[4];    // aj, ak, al, ai
  const float* W1[4];   // [128][3]  (j,k,l,i)
  const float* b1[4];   // [128]
  const float* W2[4];   // [128][128]
  const float* b2[4];   // [128]
  const float* HW[4];   // 64x128, 32x64, 16x32, 1x16
  const float* Hb[4];
  float* out;
};

__device__ __forceinline__ float celu01(float z) {
  // celu(z, alpha=0.1) = max(z,0) + min(0.1*(exp(10z)-1), 0)
  float e = __builtin_amdgcn_exp2f(z * 14.42695040888963f);  // exp(10z)
  return fmaxf(z, 0.0f) + fminf(fmaf(0.1f, e, -0.1f), 0.0f);
}

__device__ __forceinline__ short f2bf(float f) {
  unsigned u = __builtin_bit_cast(unsigned, f);
  u += 0x7fffu + ((u >> 16) & 1u);   // RNE
  return (short)(u >> 16);
}

// Stage one species' weights into LDS: sW1 (padded f32x4), sB2, and the bf16
// W2 B-fragments in per-lane layout. Leading barrier protects prior readers,
// trailing barrier publishes.
__device__ __forceinline__ void stage_species(
    const float* W1g, const float* b1g, const float* W2g, const float* b2g,
    f32x4* sW1v, float* sB2v, short8* sBfv,
    int t, int lane, int lq, int lr, int wave) {
  __syncthreads();
  if (t < 128) {
    const float* w = W1g + t * 3;
    f32x4 v;
    v.x = w[0]; v.y = w[1]; v.z = w[2]; v.w = b1g[t];
    sW1v[t + (t >> 3)] = v;
    sB2v[t] = b2g[t];
  }
  // wave -> (wcp = wave>>1, obs {2*(wave&1), +1}): 8 frags per wave
  const int wcp = wave >> 1;
  const int ob0 = (wave & 1) * 2;
#pragma unroll
  for (int oo = 0; oo < 2; ++oo) {
    const int ob = ob0 + oo;
#pragma unroll
    for (int kb = 0; kb < 4; ++kb) {
      const f32x4* src = (const f32x4*)(W2g + (wcp * 64 + ob * 16 + lr) * 128 + kb * 32 + lq * 8);
      f32x4 lo = src[0], hi = src[1];
      short8 f;
      f[0] = f2bf(lo.x); f[1] = f2bf(lo.y); f[2] = f2bf(lo.z); f[3] = f2bf(lo.w);
      f[4] = f2bf(hi.x); f[5] = f2bf(hi.y); f[6] = f2bf(hi.z); f[7] = f2bf(hi.w);
      sBfv[(wcp * 16 + ob * 4 + kb) * 64 + lane] = f;
    }
  }
  __syncthreads();
}

extern "C" __global__ __launch_bounds__(256, 2)
void dart_fused(DartParams p) {
  __shared__ __align__(16) char lds[LDS_BYTES];
  short8* sBfv = (short8*)lds;
  f32x4*  sW1v = (f32x4*)(lds + 32768);
  float*  sB2v = (float*)(lds + 35072);
  float*  sAtm = (float*)(lds + 35584);   // [G_*128]
  float*  sIm  = (float*)(lds + 39680);   // [G_]
  float*  sH1  = (float*)lds;             // [G_*64]  (after species)
  float*  sH2  = (float*)(lds + 2048);    // [G_*32]
  float*  sH3  = (float*)(lds + 3072);    // [G_*16]

  const int t    = threadIdx.x;
  const int lane = t & 63;
  const int wave = t >> 6;       // 0..3
  const int wr   = wave >> 1;    // row half (0,1)
  const int wc   = wave & 1;     // col half (0,1)
  const int lq   = lane >> 4;    // lane quarter
  const int lr   = lane & 15;
  const int atom0 = (int)blockIdx.x * G_;

  for (int i = t; i < G_ * 128; i += 256) sAtm[i] = 0.0f;

  // ---------------- species j, k, l ----------------
#pragma unroll 1
  for (int s = 0; s < 3; ++s) {
    stage_species(p.W1[s], p.b1[s], p.W2[s], p.b2[s],
                  sW1v, sB2v, sBfv, t, lane, lq, lr, wave);

    float b2r[4];
#pragma unroll
    for (int ob = 0; ob < 4; ++ob) b2r[ob] = sB2v[wc * 64 + ob * 16 + lr];

    const float* X = p.x[s];

    // prefetch atom 0's x rows
    float px[2][3];
#pragma unroll
    for (int rb = 0; rb < 2; ++rb) {
      const float* xp = X + (atom0 * 64 + wr * 32 + rb * 16 + lr) * 3;
      px[rb][0] = xp[0]; px[rb][1] = xp[1]; px[rb][2] = xp[2];
    }

#pragma unroll 1
    for (int g = 0; g < G_; ++g) {
      float x0[2], x1[2], x2[2];
      bool mA[2];
#pragma unroll
      for (int rb = 0; rb < 2; ++rb) {
        x0[rb] = px[rb][0]; x1[rb] = px[rb][1]; x2[rb] = px[rb][2];
        mA[rb] = ((x0[rb] + x1[rb] + x2[rb]) != 0.0f);
      }
      if (g + 1 < G_) {
#pragma unroll
        for (int rb = 0; rb < 2; ++rb) {
          const float* xp = X + ((atom0 + g + 1) * 64 + wr * 32 + rb * 16 + lr) * 3;
          px[rb][0] = xp[0]; px[rb][1] = xp[1]; px[rb][2] = xp[2];
        }
      }
      const unsigned long long mb0 = __ballot(mA[0]);
      const unsigned long long mb1 = __ballot(mA[1]);

      // ---- layer 1 + celu + pack, A-frag layout, w reads shared across rb ----
      short8 af0[4], af1[4];
#pragma unroll
      for (int kb = 0; kb < 4; ++kb) {
        const f32x4* wrow = sW1v + kb * 36 + lq * 9;   // padded index
        short8 f0, f1;
#pragma unroll
        for (int e = 0; e < 8; ++e) {
          f32x4 w = wrow[e];
          f0[e] = f2bf(celu01(fmaf(x0[0], w.x, fmaf(x1[0], w.y, fmaf(x2[0], w.z, w.w)))));
          f1[e] = f2bf(celu01(fmaf(x0[1], w.x, fmaf(x1[1], w.y, fmaf(x2[1], w.z, w.w)))));
        }
        af0[kb] = f0; af1[kb] = f1;
      }

      // ---- per-ob: JIT B-frag reads, 8 MFMAs, immediate epilogue ----
#pragma unroll
      for (int ob = 0; ob < 4; ++ob) {
        const short8* fb = &sBfv[(wc * 16 + ob * 4) * 64 + lane];
        f32x4 a0 = {0.0f, 0.0f, 0.0f, 0.0f};
        f32x4 a1 = {0.0f, 0.0f, 0.0f, 0.0f};
#pragma unroll
        for (int kb = 0; kb < 4; ++kb) {
          short8 fr = fb[kb * 64];
          a0 = __builtin_amdgcn_mfma_f32_16x16x32_bf16(af0[kb], fr, a0, 0, 0, 0);
          a1 = __builtin_amdgcn_mfma_f32_16x16x32_bf16(af1[kb], fr, a1, 0, 0, 0);
        }
        const int col = wc * 64 + ob * 16 + lr;
        float part = 0.0f;
#pragma unroll
        for (int j = 0; j < 4; ++j) {
          const int bit = lq * 4 + j;
          float v0 = celu01(a0[j] + b2r[ob]);
          float v1 = celu01(a1[j] + b2r[ob]);
          part += ((mb0 >> bit) & 1ull) ? v0 : 0.0f;
          part += ((mb1 >> bit) & 1ull) ? v1 : 0.0f;
        }
        part += __shfl_xor(part, 16, 64);
        part += __shfl_xor(part, 32, 64);
        if (lane < 16) atomicAdd(&sAtm[g * 128 + col], part);
      }
    }
  }

  // ---------------- species i: one 16-row GEMM (rows = atoms) ----------------
  {
    stage_species(p.W1[3], p.b1[3], p.W2[3], p.b2[3],
                  sW1v, sB2v, sBfv, t, lane, lq, lr, wave);
    // (stage's barriers also guarantee all j/k/l sAtm atomics are complete)

    const int ri = min(atom0 + lr, NATOMS - 1);
    const float* xp = p.x[3] + ri * 3;
    const float x0 = xp[0], x1 = xp[1], x2 = xp[2];
    const bool mI = ((x0 + x1 + x2) != 0.0f);
    const unsigned long long mbi = __ballot(mI);

    short8 af[4];
#pragma unroll
    for (int kb = 0; kb < 4; ++kb) {
      const f32x4* wrow = sW1v + kb * 36 + lq * 9;
      short8 f;
#pragma unroll
      for (int e = 0; e < 8; ++e) {
        f32x4 w = wrow[e];
        f[e] = f2bf(celu01(fmaf(x0, w.x, fmaf(x1, w.y, fmaf(x2, w.z, w.w)))));
      }
      af[kb] = f;
    }
    f32x4 acc[4];
#pragma unroll
    for (int ob = 0; ob < 4; ++ob) {
      const short8* fb = &sBfv[(wc * 16 + ob * 4) * 64 + lane];
      f32x4 a = {0.0f, 0.0f, 0.0f, 0.0f};
#pragma unroll
      for (int kb = 0; kb < 4; ++kb)
        a = __builtin_amdgcn_mfma_f32_16x16x32_bf16(af[kb], fb[kb * 64], a, 0, 0, 0);
      acc[ob] = a;
    }
    if (wave == 0 && t < G_) sIm[t] = mI ? 1.0f : 0.0f;
    if (wr == 0) {
#pragma unroll
      for (int ob = 0; ob < 4; ++ob) {
        const int col = wc * 64 + ob * 16 + lr;
        const float b2v = sB2v[col];
#pragma unroll
        for (int j = 0; j < 4; ++j) {
          const int g = lq * 4 + j;
          if (g < G_) {
            float m = ((mbi >> g) & 1ull) ? 1.0f : 0.0f;
            sAtm[g * 128 + col] += celu01(acc[ob][j] + b2v) * m;
          }
        }
      }
    }
    __syncthreads();   // sAtm final; sBf reads done (head reuses that space)
  }

  // ---------------- head MLP: 128 -> 64 -> 32 -> 16 -> 1 ----------------
  {
    const int g = t >> 4, u = t & 15;
    const bool act = (g < G_);
    if (act) {
      const f32x4* atm4 = (const f32x4*)(sAtm + g * 128);
#pragma unroll
      for (int rep = 0; rep < 4; ++rep) {
        const int o = rep * 16 + u;
        const f32x4* w4 = (const f32x4*)(p.HW[0] + o * 128);
        float z = p.Hb[0][o];
#pragma unroll 8
        for (int c = 0; c < 32; ++c) {
          f32x4 a = atm4[c], w = w4[c];
          z = fmaf(a.x, w.x, fmaf(a.y, w.y, fmaf(a.z, w.z, fmaf(a.w, w.w, z))));
        }
        sH1[g * 64 + o] = celu01(z);
      }
    }
    __syncthreads();
    if (act) {
      const f32x4* h14 = (const f32x4*)(sH1 + g * 64);
#pragma unroll
      for (int rep = 0; rep < 2; ++rep) {
        const int o = rep * 16 + u;
        const f32x4* w4 = (const f32x4*)(p.HW[1] + o * 64);
        float z = p.Hb[1][o];
#pragma unroll
        for (int c = 0; c < 16; ++c) {
          f32x4 a = h14[c], w = w4[c];
          z = fmaf(a.x, w.x, fmaf(a.y, w.y, fmaf(a.z, w.z, fmaf(a.w, w.w, z))));
        }
        sH2[g * 32 + o] = celu01(z);
      }
    }
    __syncthreads();
    if (act) {
      const f32x4* h24 = (const f32x4*)(sH2 + g * 32);
      const f32x4* w4 = (const f32x4*)(p.HW[2] + u * 32);
      float z = p.Hb[2][u];
#pragma unroll
      for (int c = 0; c < 8; ++c) {
        f32x4 a = h24[c], w = w4[c];
        z = fmaf(a.x, w.x, fmaf(a.y, w.y, fmaf(a.z, w.z, fmaf(a.w, w.w, z))));
      }
      sH3[g * 16 + u] = celu01(z);
    }
    __syncthreads();
    if (act && u == 0) {
      const f32x4* h34 = (const f32x4*)(sH3 + g * 16);
      const f32x4* w4 = (const f32x4*)p.HW[3];
      float z = p.Hb[3][0];
#pragma unroll
      for (int c = 0; c < 4; ++c) {
        f32x4 a = h34[c], w = w4[c];
        z = fmaf(a.x, w.x, fmaf(a.y, w.y, fmaf(a.z, w.z, fmaf(a.w, w.w, z))));
      }
      p.out[atom0 + g] = z * sIm[g];
    }
  }
}

extern "C" void kernel_launch(void* const* d_in, const int* in_sizes, int n_in,
                              void* d_out, int out_size, void* d_ws, size_t ws_size,
                              hipStream_t stream) {
  (void)in_sizes; (void)n_in; (void)out_size; (void)d_ws; (void)ws_size;
  DartParams p;
  // dict order: ai aj ak al | Wi1 bi1 Wi2 bi2 | Wj1 bj1 Wj2 bj2 | Wk1 bk1 Wk2 bk2
  //             | Wl1 bl1 Wl2 bl2 | W1 b1 W2 b2 W3 b3 W4 b4
  p.x[0] = (const float*)d_in[1];   // aj
  p.x[1] = (const float*)d_in[2];   // ak
  p.x[2] = (const float*)d_in[3];   // al
  p.x[3] = (const float*)d_in[0];   // ai
  p.W1[0] = (const float*)d_in[8];  p.b1[0] = (const float*)d_in[9];
  p.W2[0] = (const float*)d_in[10]; p.b2[0] = (const float*)d_in[11];
  p.W1[1] = (const float*)d_in[12]; p.b1[1] = (const float*)d_in[13];
  p.W2[1] = (const float*)d_in[14]; p.b2[1] = (const float*)d_in[15];
  p.W1[2] = (const float*)d_in[16]; p.b1[2] = (const float*)d_in[17];
  p.W2[2] = (const float*)d_in[18]; p.b2[2] = (const float*)d_in[19];
  p.W1[3] = (const float*)d_in[4];  p.b1[3] = (const float*)d_in[5];
  p.W2[3] = (const float*)d_in[6];  p.b2[3] = (const float*)d_in[7];
  p.HW[0] = (const float*)d_in[20]; p.Hb[0] = (const float*)d_in[21];
  p.HW[1] = (const float*)d_in[22]; p.Hb[1] = (const float*)d_in[23];
  p.HW[2] = (const float*)d_in[24]; p.Hb[2] = (const float*)d_in[25];
  p.HW[3] = (const float*)d_in[26]; p.Hb[3] = (const float*)d_in[27];
  p.out = (float*)d_out;

  dart_fused<<<dim3(NATOMS / G_), dim3(256), 0, stream>>>(p);
}

// Round 5
// 184.576 us; speedup vs baseline: 7.7239x; 1.3476x over previous
//
#include <hip/hip_runtime.h>

// DART_Net fused kernel, MI355X (gfx950). Round 5.
// B=64, N=128, M=64, LH=LO=128. Output [B*N] fp32.
//
// R5 vs R4 (R4: 249 us, VALU-bound 76%, MFMA 8%, occ 27%):
//  - Wave split changed to rows: wave w owns rows w*16..w*16+15 x all 128
//    cols. Kills the 2x layer-1 redundancy of the old 2x2 (row,col) split.
//  - v_cvt_pk_bf16_f32 inline asm replaces manual RNE bit-twiddle (1 instr
//    per 2 values instead of ~9).
//  - Atom-PAIR inner loop: one W1/B-frag LDS read serves 2 atoms (DS pipe
//    was heading to co-bottleneck: 48 -> 24 b128 reads/atom/wave).
//  - b2 bias folded into MFMA acc init (splat as C-in); row masks
//    precomputed as floats once per atom, applied with v_fmac (replaces
//    per-output 64-bit shift+select chains).

typedef __attribute__((ext_vector_type(8))) short short8;   // bf16x8 frag (4 VGPR)
typedef __attribute__((ext_vector_type(4))) float f32x4;    // acc frag / float4
typedef __attribute__((ext_vector_type(4))) unsigned uint4v;

#define G_ 8
#define NATOMS (64 * 128)

// LDS layout (bytes):
//   [    0, 32768)  sBf  : bf16 B-frags [ob*4+kb][lane] (16B each)
//                   (after species done, reused: sH1 @0, sH2 @2048, sH3 @3072)
//   [32768, 35072)  sW1  : f32x4[144] {w0,w1,w2,b1}, padded idx = c + (c>>3)
//   [35072, 35584)  sB2  : float[128]
//   [35584, 39680)  sAtm : float[G_][128]
//   [39680, 39712)  sIm  : float[G_]
#define LDS_BYTES 39712

struct DartParams {
  const float* x[4];    // aj, ak, al, ai
  const float* W1[4];   // [128][3]  (j,k,l,i)
  const float* b1[4];   // [128]
  const float* W2[4];   // [128][128]
  const float* b2[4];   // [128]
  const float* HW[4];   // 64x128, 32x64, 16x32, 1x16
  const float* Hb[4];
  float* out;
};

__device__ __forceinline__ float celu01(float z) {
  // celu(z, alpha=0.1) = max(z,0) + min(0.1*(exp(10z)-1), 0)
  float e = __builtin_amdgcn_exp2f(z * 14.42695040888963f);  // exp(10z)
  return fmaxf(z, 0.0f) + fminf(fmaf(0.1f, e, -0.1f), 0.0f);
}

// packed f32x2 -> bf16x2 (gfx950 v_cvt_pk_bf16_f32; no builtin exists)
__device__ __forceinline__ unsigned cvtpk(float a, float b) {
  unsigned r;
  asm("v_cvt_pk_bf16_f32 %0, %1, %2" : "=v"(r) : "v"(a), "v"(b));
  return r;
}
__device__ __forceinline__ short8 pack4(unsigned a, unsigned b, unsigned c, unsigned d) {
  uint4v u = {a, b, c, d};
  return __builtin_bit_cast(short8, u);
}

// Stage one species' weights into LDS: sW1 (padded f32x4), sB2, and bf16 W2
// B-fragments [ob*4+kb][lane]. Leading barrier protects prior readers,
// trailing barrier publishes.
__device__ __forceinline__ void stage_species(
    const float* W1g, const float* b1g, const float* W2g, const float* b2g,
    f32x4* sW1v, float* sB2v, short8* sBfv,
    int t, int lane, int lq, int lr, int wave) {
  __syncthreads();
  if (t < 128) {
    const float* w = W1g + t * 3;
    f32x4 v;
    v.x = w[0]; v.y = w[1]; v.z = w[2]; v.w = b1g[t];
    sW1v[t + (t >> 3)] = v;
    sB2v[t] = b2g[t];
  }
#pragma unroll
  for (int ff = 0; ff < 8; ++ff) {
    const int f  = wave * 8 + ff;
    const int ob = f >> 2, kb = f & 3;
    const f32x4* src = (const f32x4*)(W2g + (ob * 16 + lr) * 128 + kb * 32 + lq * 8);
    f32x4 lo = src[0], hi = src[1];
    sBfv[f * 64 + lane] = pack4(cvtpk(lo.x, lo.y), cvtpk(lo.z, lo.w),
                                cvtpk(hi.x, hi.y), cvtpk(hi.z, hi.w));
  }
  __syncthreads();
}

extern "C" __global__ __launch_bounds__(256, 2)
void dart_fused(DartParams p) {
  __shared__ __align__(16) char lds[LDS_BYTES];
  short8* sBfv = (short8*)lds;
  f32x4*  sW1v = (f32x4*)(lds + 32768);
  float*  sB2v = (float*)(lds + 35072);
  float*  sAtm = (float*)(lds + 35584);   // [G_*128]
  float*  sIm  = (float*)(lds + 39680);   // [G_]
  float*  sH1  = (float*)lds;             // [G_*64]  (after species)
  float*  sH2  = (float*)(lds + 2048);    // [G_*32]
  float*  sH3  = (float*)(lds + 3072);    // [G_*16]

  const int t    = threadIdx.x;
  const int lane = t & 63;
  const int wave = t >> 6;       // 0..3 -> row block wave*16
  const int lq   = lane >> 4;    // lane quarter
  const int lr   = lane & 15;
  const int atom0 = (int)blockIdx.x * G_;

  for (int i = t; i < G_ * 128; i += 256) sAtm[i] = 0.0f;

  // ---------------- species j, k, l ----------------
#pragma unroll 1
  for (int s = 0; s < 3; ++s) {
    stage_species(p.W1[s], p.b1[s], p.W2[s], p.b2[s],
                  sW1v, sB2v, sBfv, t, lane, lq, lr, wave);

    float b2r[8];
#pragma unroll
    for (int ob = 0; ob < 8; ++ob) b2r[ob] = sB2v[ob * 16 + lr];

    const float* X = p.x[s];
    // per-lane row within each atom: wave*16 + lr (lq groups replicate)
    const int rowoff = wave * 16 + lr;

    // prefetch pair 0
    float pxa[3], pxb[3];
    {
      const float* xa = X + ((atom0 + 0) * 64 + rowoff) * 3;
      const float* xb = X + ((atom0 + 1) * 64 + rowoff) * 3;
      pxa[0] = xa[0]; pxa[1] = xa[1]; pxa[2] = xa[2];
      pxb[0] = xb[0]; pxb[1] = xb[1]; pxb[2] = xb[2];
    }

#pragma unroll 1
    for (int pp = 0; pp < G_ / 2; ++pp) {
      const int g0 = 2 * pp, g1 = 2 * pp + 1;
      const float xa0 = pxa[0], xa1 = pxa[1], xa2 = pxa[2];
      const float xb0 = pxb[0], xb1 = pxb[1], xb2 = pxb[2];
      if (pp + 1 < G_ / 2) {
        const float* xa = X + ((atom0 + g0 + 2) * 64 + rowoff) * 3;
        const float* xb = X + ((atom0 + g1 + 2) * 64 + rowoff) * 3;
        pxa[0] = xa[0]; pxa[1] = xa[1]; pxa[2] = xa[2];
        pxb[0] = xb[0]; pxb[1] = xb[1]; pxb[2] = xb[2];
      }
      const unsigned mwa = (unsigned)__ballot((xa0 + xa1 + xa2) != 0.0f);
      const unsigned mwb = (unsigned)__ballot((xb0 + xb1 + xb2) != 0.0f);
      float mra[4], mrb[4];
#pragma unroll
      for (int j = 0; j < 4; ++j) {
        mra[j] = (float)((mwa >> (lq * 4 + j)) & 1u);
        mrb[j] = (float)((mwb >> (lq * 4 + j)) & 1u);
      }

      // ---- layer 1 + celu + cvt_pk pack, A-frag layout, both atoms ----
      short8 afa[4], afb[4];
#pragma unroll
      for (int kb = 0; kb < 4; ++kb) {
        const f32x4* wrow = sW1v + kb * 36 + lq * 9;   // padded index
        unsigned ua[4], ub[4];
#pragma unroll
        for (int e2 = 0; e2 < 4; ++e2) {
          f32x4 wA = wrow[2 * e2], wB = wrow[2 * e2 + 1];
          float aA = celu01(fmaf(xa0, wA.x, fmaf(xa1, wA.y, fmaf(xa2, wA.z, wA.w))));
          float aB = celu01(fmaf(xa0, wB.x, fmaf(xa1, wB.y, fmaf(xa2, wB.z, wB.w))));
          ua[e2] = cvtpk(aA, aB);
          float bA = celu01(fmaf(xb0, wA.x, fmaf(xb1, wA.y, fmaf(xb2, wA.z, wA.w))));
          float bB = celu01(fmaf(xb0, wB.x, fmaf(xb1, wB.y, fmaf(xb2, wB.z, wB.w))));
          ub[e2] = cvtpk(bA, bB);
        }
        afa[kb] = pack4(ua[0], ua[1], ua[2], ua[3]);
        afb[kb] = pack4(ub[0], ub[1], ub[2], ub[3]);
      }

      // ---- per-ob: shared B-frag reads, 8 MFMAs (2 atoms), epilogue ----
#pragma unroll
      for (int ob = 0; ob < 8; ++ob) {
        const short8* fb = sBfv + (ob * 4) * 64 + lane;
        const float bv = b2r[ob];
        f32x4 a0 = {bv, bv, bv, bv};
        f32x4 a1 = a0;
#pragma unroll
        for (int kb = 0; kb < 4; ++kb) {
          short8 fr = fb[kb * 64];
          a0 = __builtin_amdgcn_mfma_f32_16x16x32_bf16(afa[kb], fr, a0, 0, 0, 0);
          a1 = __builtin_amdgcn_mfma_f32_16x16x32_bf16(afb[kb], fr, a1, 0, 0, 0);
        }
        float p0 = 0.0f, p1 = 0.0f;
#pragma unroll
        for (int j = 0; j < 4; ++j) {
          p0 = fmaf(celu01(a0[j]), mra[j], p0);
          p1 = fmaf(celu01(a1[j]), mrb[j], p1);
        }
        p0 += __shfl_xor(p0, 16, 64);
        p0 += __shfl_xor(p0, 32, 64);
        p1 += __shfl_xor(p1, 16, 64);
        p1 += __shfl_xor(p1, 32, 64);
        const int col = ob * 16 + lr;
        if (lane < 16) {
          atomicAdd(&sAtm[g0 * 128 + col], p0);
          atomicAdd(&sAtm[g1 * 128 + col], p1);
        }
      }
    }
  }

  // ---------------- species i: one 16-row GEMM (rows = atoms) ----------------
  {
    stage_species(p.W1[3], p.b1[3], p.W2[3], p.b2[3],
                  sW1v, sB2v, sBfv, t, lane, lq, lr, wave);
    // (leading barrier also guarantees all j/k/l sAtm atomics complete)

    const int ri = min(atom0 + lr, NATOMS - 1);
    const float* xp = p.x[3] + ri * 3;
    const float x0 = xp[0], x1 = xp[1], x2 = xp[2];
    const unsigned mbi = (unsigned)__ballot((x0 + x1 + x2) != 0.0f);

    short8 af[4];
#pragma unroll
    for (int kb = 0; kb < 4; ++kb) {
      const f32x4* wrow = sW1v + kb * 36 + lq * 9;
      unsigned u[4];
#pragma unroll
      for (int e2 = 0; e2 < 4; ++e2) {
        f32x4 wA = wrow[2 * e2], wB = wrow[2 * e2 + 1];
        float cA = celu01(fmaf(x0, wA.x, fmaf(x1, wA.y, fmaf(x2, wA.z, wA.w))));
        float cB = celu01(fmaf(x0, wB.x, fmaf(x1, wB.y, fmaf(x2, wB.z, wB.w))));
        u[e2] = cvtpk(cA, cB);
      }
      af[kb] = pack4(u[0], u[1], u[2], u[3]);
    }
    // each wave handles 2 output blocks: ob = wave*2, wave*2+1 (disjoint cols
    // across waves -> no atomics needed)
#pragma unroll
    for (int oo = 0; oo < 2; ++oo) {
      const int ob = wave * 2 + oo;
      const int col = ob * 16 + lr;
      const float bv = sB2v[col];
      const short8* fb = sBfv + (ob * 4) * 64 + lane;
      f32x4 a = {bv, bv, bv, bv};
#pragma unroll
      for (int kb = 0; kb < 4; ++kb)
        a = __builtin_amdgcn_mfma_f32_16x16x32_bf16(af[kb], fb[kb * 64], a, 0, 0, 0);
#pragma unroll
      for (int j = 0; j < 4; ++j) {
        const int g = lq * 4 + j;
        if (g < G_) {
          float m = (float)((mbi >> g) & 1u);
          sAtm[g * 128 + col] += celu01(a[j]) * m;
        }
      }
    }
    if (wave == 0 && t < G_) sIm[t] = (float)((mbi >> t) & 1u);
    __syncthreads();   // sAtm final; sBf reads done (head reuses that space)
  }

  // ---------------- head MLP: 128 -> 64 -> 32 -> 16 -> 1 ----------------
  {
    const int g = t >> 4, u = t & 15;
    const bool act = (g < G_);
    if (act) {
      const f32x4* atm4 = (const f32x4*)(sAtm + g * 128);
#pragma unroll
      for (int rep = 0; rep < 4; ++rep) {
        const int o = rep * 16 + u;
        const f32x4* w4 = (const f32x4*)(p.HW[0] + o * 128);
        float z = p.Hb[0][o];
#pragma unroll 8
        for (int c = 0; c < 32; ++c) {
          f32x4 a = atm4[c], w = w4[c];
          z = fmaf(a.x, w.x, fmaf(a.y, w.y, fmaf(a.z, w.z, fmaf(a.w, w.w, z))));
        }
        sH1[g * 64 + o] = celu01(z);
      }
    }
    __syncthreads();
    if (act) {
      const f32x4* h14 = (const f32x4*)(sH1 + g * 64);
#pragma unroll
      for (int rep = 0; rep < 2; ++rep) {
        const int o = rep * 16 + u;
        const f32x4* w4 = (const f32x4*)(p.HW[1] + o * 64);
        float z = p.Hb[1][o];
#pragma unroll
        for (int c = 0; c < 16; ++c) {
          f32x4 a = h14[c], w = w4[c];
          z = fmaf(a.x, w.x, fmaf(a.y, w.y, fmaf(a.z, w.z, fmaf(a.w, w.w, z))));
        }
        sH2[g * 32 + o] = celu01(z);
      }
    }
    __syncthreads();
    if (act) {
      const f32x4* h24 = (const f32x4*)(sH2 + g * 32);
      const f32x4* w4 = (const f32x4*)(p.HW[2] + u * 32);
      float z = p.Hb[2][u];
#pragma unroll
      for (int c = 0; c < 8; ++c) {
        f32x4 a = h24[c], w = w4[c];
        z = fmaf(a.x, w.x, fmaf(a.y, w.y, fmaf(a.z, w.z, fmaf(a.w, w.w, z))));
      }
      sH3[g * 16 + u] = celu01(z);
    }
    __syncthreads();
    if (act && u == 0) {
      const f32x4* h34 = (const f32x4*)(sH3 + g * 16);
      const f32x4* w4 = (const f32x4*)p.HW[3];
      float z = p.Hb[3][0];
#pragma unroll
      for (int c = 0; c < 4; ++c) {
        f32x4 a = h34[c], w = w4[c];
        z = fmaf(a.x, w.x, fmaf(a.y, w.y, fmaf(a.z, w.z, fmaf(a.w, w.w, z))));
      }
      p.out[atom0 + g] = z * sIm[g];
    }
  }
}

extern "C" void kernel_launch(void* const* d_in, const int* in_sizes, int n_in,
                              void* d_out, int out_size, void* d_ws, size_t ws_size,
                              hipStream_t stream) {
  (void)in_sizes; (void)n_in; (void)out_size; (void)d_ws; (void)ws_size;
  DartParams p;
  // dict order: ai aj ak al | Wi1 bi1 Wi2 bi2 | Wj1 bj1 Wj2 bj2 | Wk1 bk1 Wk2 bk2
  //             | Wl1 bl1 Wl2 bl2 | W1 b1 W2 b2 W3 b3 W4 b4
  p.x[0] = (const float*)d_in[1];   // aj
  p.x[1] = (const float*)d_in[2];   // ak
  p.x[2] = (const float*)d_in[3];   // al
  p.x[3] = (const float*)d_in[0];   // ai
  p.W1[0] = (const float*)d_in[8];  p.b1[0] = (const float*)d_in[9];
  p.W2[0] = (const float*)d_in[10]; p.b2[0] = (const float*)d_in[11];
  p.W1[1] = (const float*)d_in[12]; p.b1[1] = (const float*)d_in[13];
  p.W2[1] = (const float*)d_in[14]; p.b2[1] = (const float*)d_in[15];
  p.W1[2] = (const float*)d_in[16]; p.b1[2] = (const float*)d_in[17];
  p.W2[2] = (const float*)d_in[18]; p.b2[2] = (const float*)d_in[19];
  p.W1[3] = (const float*)d_in[4];  p.b1[3] = (const float*)d_in[5];
  p.W2[3] = (const float*)d_in[6];  p.b2[3] = (const float*)d_in[7];
  p.HW[0] = (const float*)d_in[20]; p.Hb[0] = (const float*)d_in[21];
  p.HW[1] = (const float*)d_in[22]; p.Hb[1] = (const float*)d_in[23];
  p.HW[2] = (const float*)d_in[24]; p.Hb[2] = (const float*)d_in[25];
  p.HW[3] = (const float*)d_in[26]; p.Hb[3] = (const float*)d_in[27];
  p.out = (float*)d_out;

  dart_fused<<<dim3(NATOMS / G_), dim3(256), 0, stream>>>(p);
}